// Round 10
// baseline (287.982 us; speedup 1.0000x reference)
//
#include <hip/hip_runtime.h>

#define N_NODES 40000
#define M_PAD   40064   // 313 * 128
#define N_EDGES 320000
#define N_GRAPHS 64
#define IN_DIM 128
#define HID4 256
#define OUT_DIM 128
#define LN_EPS 1e-5f

typedef short  s16x8  __attribute__((ext_vector_type(8)));
typedef __bf16 bf16x8 __attribute__((ext_vector_type(8)));
typedef float  f32x4  __attribute__((ext_vector_type(4)));

__device__ __forceinline__ unsigned short f2b(float f) {
    unsigned int u = __builtin_bit_cast(unsigned int, f);
    u += 0x7fffu + ((u >> 16) & 1u);   // round-to-nearest-even
    return (unsigned short)(u >> 16);
}
__device__ __forceinline__ float b2f(unsigned short h) {
    unsigned int u = (unsigned int)h << 16;
    return __builtin_bit_cast(float, u);
}

// direct global->LDS 16B DMA; lds base wave-uniform, HW scatters lane*16
__device__ __forceinline__ void gll16(const unsigned short* g, short* lds_base) {
    __builtin_amdgcn_global_load_lds(
        (const __attribute__((address_space(1))) unsigned int*)g,
        (__attribute__((address_space(3))) unsigned int*)lds_base, 16, 0, 0);
}

// ---------------- fused prep: x->bf16, weights->bf16 transposed, degree histograms ----

#define XN (N_NODES * IN_DIM)          // 5,120,000
#define WN 229376                      // 32768*3 + 131072
#define PREP_TOT (XN + WN + N_EDGES)

__global__ void prep_all(const float* __restrict__ x, const float* __restrict__ W1,
                         const float* __restrict__ fc1, const float* __restrict__ W2,
                         const float* __restrict__ W3,
                         const int* __restrict__ src, const int* __restrict__ dst,
                         unsigned short* __restrict__ xb, unsigned short* __restrict__ W1t,
                         unsigned short* __restrict__ fc1t, unsigned short* __restrict__ W2t,
                         unsigned short* __restrict__ W3t,
                         int* __restrict__ cnt_out, int* __restrict__ cnt_in) {
    int idx = blockIdx.x * 256 + threadIdx.x;
    if (idx < XN) { xb[idx] = f2b(x[idx]); return; }
    int j = idx - XN;
    if (j < 32768) { int k = j >> 8, n = j & 255; W1t[n * 128 + k] = f2b(W1[j]); return; }
    j -= 32768;
    if (j < 32768) { int k = j >> 8, n = j & 255; fc1t[n * 128 + k] = f2b(fc1[j]); return; }
    j -= 32768;
    if (j < 131072) { int k = j >> 8, n = j & 255; W2t[n * 512 + k] = f2b(W2[j]); return; }
    j -= 131072;
    if (j < 32768) { int k = j >> 7, n = j & 127; W3t[n * 256 + k] = f2b(W3[j]); return; }
    j -= 32768;
    if (j < N_EDGES) {
        atomicAdd(&cnt_out[src[j]], 1);
        atomicAdd(&cnt_in[dst[j]], 1);
    }
}

// 40 blocks x 1024 threads: block b computes its own prefix over cnt_in[0..b*1000),
// then excl-scans its 1000 elements -> off ; also inv-sqrt degrees
__global__ void scan_final(const int* __restrict__ cnt_in, const int* __restrict__ cnt_out,
                           int* __restrict__ off,
                           float* __restrict__ out_inv, float* __restrict__ in_inv) {
    int b = blockIdx.x, tid = threadIdx.x;
    int lane = tid & 63, wv = tid >> 6;
    __shared__ int red[16];
    __shared__ int pre_s;
    // block-wide sum of cnt_in[0 .. b*1000)
    int lim = b * 1000;
    int s = 0;
    for (int i = tid; i < lim; i += 1024) s += cnt_in[i];
#pragma unroll
    for (int m = 1; m < 64; m <<= 1) s += __shfl_xor(s, m);
    if (lane == 0) red[wv] = s;
    __syncthreads();
    if (tid == 0) {
        int p = 0;
#pragma unroll
        for (int k = 0; k < 16; ++k) p += red[k];
        pre_s = p;
    }
    __syncthreads();
    int pre = pre_s;

    int i = b * 1000 + tid;
    int v = (tid < 1000) ? cnt_in[i] : 0;
    int x = v;
#pragma unroll
    for (int ofs = 1; ofs < 64; ofs <<= 1) {
        int t = __shfl_up(x, ofs);
        if (lane >= ofs) x += t;
    }
    __shared__ int wsum[16];
    if (lane == 63) wsum[wv] = x;
    __syncthreads();
    if (wv == 0 && lane < 16) {
        int ss = wsum[lane];
#pragma unroll
        for (int ofs = 1; ofs < 16; ofs <<= 1) {
            int t = __shfl_up(ss, ofs);
            if (lane >= ofs) ss += t;
        }
        wsum[lane] = ss;
    }
    __syncthreads();
    int incl = pre + (wv > 0 ? wsum[wv - 1] : 0) + x;
    if (tid < 1000) {
        off[i] = incl - v;   // exclusive
        in_inv[i] = rsqrtf(fmaxf((float)v, 1.0f));
        out_inv[i] = rsqrtf(fmaxf((float)cnt_out[i], 1.0f));
    }
    if (b == 39 && tid == 999) off[N_NODES] = incl;
}

// consumes cnt_in as countdown cursor; computes ew inline; emits packed (src, weight) records
__global__ void csr_fill(const int* __restrict__ src, const int* __restrict__ dst,
                         const float* __restrict__ w, const float* __restrict__ out_inv,
                         const int* __restrict__ off, int* __restrict__ cnt_in,
                         int2* __restrict__ es1, int2* __restrict__ es23) {
    int e = blockIdx.x * 256 + threadIdx.x;
    if (e >= N_EDGES) return;
    int d = dst[e];
    int slot = off[d] + atomicSub(&cnt_in[d], 1) - 1;
    int s = src[e];
    float4 v = ((const float4*)w)[e];
    float wv = fmaxf(fmaxf(v.x, v.y), fmaxf(v.z, v.w));
    es1[slot] = make_int2(s, __float_as_int(wv * out_inv[s]));
    es23[slot] = make_int2(s, __float_as_int(wv));
}

// ---------------- gather aggregation (NPB nodes/block, packed edges) ----------------

template <int D, int RELU, int NPB>
__global__ void gather_nodes(const unsigned short* __restrict__ h, const int* __restrict__ off,
                             const int2* __restrict__ eg, const float* __restrict__ scale,
                             unsigned short* __restrict__ outb) {
    int t = threadIdx.x;  // D/2 threads
    int n0 = blockIdx.x * NPB;
    int n1 = n0 + NPB;
    if (n1 > N_NODES) n1 = N_NODES;
    const unsigned int* hu = (const unsigned int*)h;
    for (int n = n0; n < n1; ++n) {
        int b = off[n], e = off[n + 1];
        float a0 = 0.0f, a1 = 0.0f;
        int i = b;
        for (; i + 3 < e; i += 4) {
            int2 e0 = eg[i], e1 = eg[i + 1], e2 = eg[i + 2], e3 = eg[i + 3];
            unsigned int p0 = hu[(size_t)e0.x * (D / 2) + t];
            unsigned int p1 = hu[(size_t)e1.x * (D / 2) + t];
            unsigned int p2 = hu[(size_t)e2.x * (D / 2) + t];
            unsigned int p3 = hu[(size_t)e3.x * (D / 2) + t];
            float w0 = __int_as_float(e0.y), w1 = __int_as_float(e1.y);
            float w2 = __int_as_float(e2.y), w3 = __int_as_float(e3.y);
            a0 += w0 * b2f((unsigned short)p0) + w1 * b2f((unsigned short)p1)
                + w2 * b2f((unsigned short)p2) + w3 * b2f((unsigned short)p3);
            a1 += w0 * b2f((unsigned short)(p0 >> 16)) + w1 * b2f((unsigned short)(p1 >> 16))
                + w2 * b2f((unsigned short)(p2 >> 16)) + w3 * b2f((unsigned short)(p3 >> 16));
        }
        for (; i < e; ++i) {
            int2 ee = eg[i];
            unsigned int p = hu[(size_t)ee.x * (D / 2) + t];
            float w0 = __int_as_float(ee.y);
            a0 += w0 * b2f((unsigned short)p);
            a1 += w0 * b2f((unsigned short)(p >> 16));
        }
        float sc = scale[n];
        a0 *= sc; a1 *= sc;
        if (RELU) { a0 = fmaxf(a0, 0.0f); a1 = fmaxf(a1, 0.0f); }
        unsigned int o = (unsigned int)f2b(a0) | ((unsigned int)f2b(a1) << 16);
        ((unsigned int*)outb)[(size_t)n * (D / 2) + t] = o;
    }
}

// ---------------- gather conv3 + fused readout (8 nodes/block, run-length atomics) ------

#define G3_NPB 8

__global__ void gather3_ro(const unsigned short* __restrict__ h, const int* __restrict__ off,
                           const int2* __restrict__ eg, const float* __restrict__ scale,
                           const int* __restrict__ gid, float* __restrict__ ro) {
    int t = threadIdx.x;  // 64 threads; cols 2t, 2t+1 (D=128)
    int n0 = blockIdx.x * G3_NPB;
    int n1 = n0 + G3_NPB;
    if (n1 > N_NODES) n1 = N_NODES;
    const unsigned int* hu = (const unsigned int*)h;
    float r0 = 0.0f, r1 = 0.0f;
    int cur = gid[n0];
    for (int n = n0; n < n1; ++n) {
        int g = gid[n];
        if (g != cur) {
            atomicAdd(&ro[cur * OUT_DIM + 2 * t], r0);
            atomicAdd(&ro[cur * OUT_DIM + 2 * t + 1], r1);
            r0 = r1 = 0.0f;
            cur = g;
        }
        int b = off[n], e = off[n + 1];
        float a0 = 0.0f, a1 = 0.0f;
        int i = b;
        for (; i + 3 < e; i += 4) {
            int2 e0 = eg[i], e1 = eg[i + 1], e2 = eg[i + 2], e3 = eg[i + 3];
            unsigned int p0 = hu[(size_t)e0.x * 64 + t];
            unsigned int p1 = hu[(size_t)e1.x * 64 + t];
            unsigned int p2 = hu[(size_t)e2.x * 64 + t];
            unsigned int p3 = hu[(size_t)e3.x * 64 + t];
            float w0 = __int_as_float(e0.y), w1 = __int_as_float(e1.y);
            float w2 = __int_as_float(e2.y), w3 = __int_as_float(e3.y);
            a0 += w0 * b2f((unsigned short)p0) + w1 * b2f((unsigned short)p1)
                + w2 * b2f((unsigned short)p2) + w3 * b2f((unsigned short)p3);
            a1 += w0 * b2f((unsigned short)(p0 >> 16)) + w1 * b2f((unsigned short)(p1 >> 16))
                + w2 * b2f((unsigned short)(p2 >> 16)) + w3 * b2f((unsigned short)(p3 >> 16));
        }
        for (; i < e; ++i) {
            int2 ee = eg[i];
            unsigned int p = hu[(size_t)ee.x * 64 + t];
            float w0 = __int_as_float(ee.y);
            a0 += w0 * b2f((unsigned short)p);
            a1 += w0 * b2f((unsigned short)(p >> 16));
        }
        float sc = scale[n];
        r0 += fmaxf(a0 * sc, 0.0f);
        r1 += fmaxf(a1 * sc, 0.0f);
    }
    atomicAdd(&ro[cur * OUT_DIM + 2 * t], r0);
    atomicAdd(&ro[cur * OUT_DIM + 2 * t + 1], r1);
}

// ---------------- MFMA bf16 GEMM core: 128x128 tile, BK=32, global_load_lds staging ------

__device__ __forceinline__ void gemm_core(short* As, short* Bs,
    const unsigned short* __restrict__ A, const unsigned short* __restrict__ Bt,
    unsigned short* __restrict__ C, const float* __restrict__ rowScaleC,
    int K, int N, int relu, int scaleC, int m0, int n0) {
    int tid = threadIdx.x;
    int lane = tid & 63, wave = tid >> 6;
    int wm = (wave >> 1) * 64, wn = (wave & 1) * 64;
    int quad = lane >> 4, r16 = lane & 15;
    f32x4 acc[4][4] = {};
    int lrow = wave * 16 + (lane >> 2);
    int kc = (lane & 3) * 8;
    short* ldsA = As + wave * 512;
    short* ldsB = Bs + wave * 512;

    for (int k0 = 0; k0 < K; k0 += 32) {
        int kk = k0 + kc;
#pragma unroll
        for (int h = 0; h < 2; ++h) {
            int r = h * 64 + lrow;
            gll16(A + (size_t)(m0 + r) * K + kk, ldsA + h * 2048);
            gll16(Bt + (size_t)(n0 + r) * K + kk, ldsB + h * 2048);
        }
        __syncthreads();
        s16x8 af[4], bfr[4];
#pragma unroll
        for (int i = 0; i < 4; ++i)
            af[i] = *(const s16x8*)(As + (wm + i * 16 + r16) * 32 + quad * 8);
#pragma unroll
        for (int j = 0; j < 4; ++j)
            bfr[j] = *(const s16x8*)(Bs + (wn + j * 16 + r16) * 32 + quad * 8);
#pragma unroll
        for (int i = 0; i < 4; ++i)
#pragma unroll
            for (int j = 0; j < 4; ++j)
                acc[i][j] = __builtin_amdgcn_mfma_f32_16x16x32_bf16(
                    __builtin_bit_cast(bf16x8, af[i]), __builtin_bit_cast(bf16x8, bfr[j]),
                    acc[i][j], 0, 0, 0);
        __syncthreads();
    }

#pragma unroll
    for (int i = 0; i < 4; ++i) {
        int mbase = m0 + wm + i * 16 + quad * 4;
#pragma unroll
        for (int r = 0; r < 4; ++r) {
            int m = mbase + r;
            float sc = scaleC ? rowScaleC[m] : 1.0f;
#pragma unroll
            for (int j = 0; j < 4; ++j) {
                float v = acc[i][j][r] * sc;
                if (relu) v = fmaxf(v, 0.0f);
                C[(size_t)m * N + n0 + wn + j * 16 + r16] = f2b(v);
            }
        }
    }
}

template <int RELU, int SCALE_C>
__global__ __launch_bounds__(256) void gemm_mfma(
    const unsigned short* __restrict__ A, const unsigned short* __restrict__ Bt,
    unsigned short* __restrict__ C, const float* __restrict__ rowScaleC, int K, int N) {
    __shared__ short As[4096];
    __shared__ short Bs[4096];
    gemm_core(As, Bs, A, Bt, C, rowScaleC, K, N, RELU, SCALE_C,
              blockIdx.x * 128, blockIdx.y * 128);
}

// -------- dual GEMM, 128x256 tile, 512 threads: conv1 (z=0, relu) / fc1+LN (z=1) ----
// Writes into interleaved x1f1[M][512]: z=0 -> cols 0..255, z=1 -> cols 256..511.

__global__ __launch_bounds__(512) void gemm_dual(
    const unsigned short* __restrict__ A0, const unsigned short* __restrict__ B0,
    const unsigned short* __restrict__ A1, const unsigned short* __restrict__ B1,
    unsigned short* __restrict__ x1f1,
    const float* __restrict__ gamma, const float* __restrict__ beta) {
    __shared__ short As[4096];   // [128][32]
    __shared__ short Bs[8192];   // [256][32]
    __shared__ float lns[128][4];
    __shared__ float lnq[128][4];
    const unsigned short* A  = blockIdx.z ? A1 : A0;
    const unsigned short* Bt = blockIdx.z ? B1 : B0;
    unsigned short* C = x1f1 + (blockIdx.z ? 256 : 0);
    int tid = threadIdx.x;
    int lane = tid & 63, wave = tid >> 6;      // 0..7
    int wm = (wave >> 2) * 64, wn = (wave & 3) * 64;
    int quad = lane >> 4, r16 = lane & 15;
    int m0 = blockIdx.x * 128;
    f32x4 acc[4][4] = {};
    int lrow = lane >> 2;
    int kc = (lane & 3) * 8;
    short* ldsA = As + wave * 512;
    short* ldsB = Bs + wave * 512;

    for (int k0 = 0; k0 < 128; k0 += 32) {
        int kk = k0 + kc;
        int rr = wave * 16 + lrow;  // 0..127
        gll16(A + (size_t)(m0 + rr) * 128 + kk, ldsA);
        gll16(Bt + (size_t)rr * 128 + kk, ldsB);
        gll16(Bt + (size_t)(128 + rr) * 128 + kk, ldsB + 4096);
        __syncthreads();
        s16x8 af[4], bfr[4];
#pragma unroll
        for (int i = 0; i < 4; ++i)
            af[i] = *(const s16x8*)(As + (wm + i * 16 + r16) * 32 + quad * 8);
#pragma unroll
        for (int j = 0; j < 4; ++j)
            bfr[j] = *(const s16x8*)(Bs + (wn + j * 16 + r16) * 32 + quad * 8);
#pragma unroll
        for (int i = 0; i < 4; ++i)
#pragma unroll
            for (int j = 0; j < 4; ++j)
                acc[i][j] = __builtin_amdgcn_mfma_f32_16x16x32_bf16(
                    __builtin_bit_cast(bf16x8, af[i]), __builtin_bit_cast(bf16x8, bfr[j]),
                    acc[i][j], 0, 0, 0);
        __syncthreads();
    }

    if (blockIdx.z == 0) {
#pragma unroll
        for (int i = 0; i < 4; ++i) {
            int mbase = m0 + wm + i * 16 + quad * 4;
#pragma unroll
            for (int r = 0; r < 4; ++r) {
                int m = mbase + r;
#pragma unroll
                for (int j = 0; j < 4; ++j)
                    C[(size_t)m * 512 + wn + j * 16 + r16] = f2b(fmaxf(acc[i][j][r], 0.0f));
            }
        }
    } else {
        // fc1: LayerNorm(affine) + relu from fp32 accumulators
#pragma unroll
        for (int i = 0; i < 4; ++i)
#pragma unroll
            for (int r = 0; r < 4; ++r) {
                float s = 0.0f, q = 0.0f;
#pragma unroll
                for (int j = 0; j < 4; ++j) { float v = acc[i][j][r]; s += v; q += v * v; }
#pragma unroll
                for (int m = 1; m < 16; m <<= 1) { s += __shfl_xor(s, m); q += __shfl_xor(q, m); }
                if (r16 == 0) {
                    int row = wm + i * 16 + quad * 4 + r;
                    lns[row][wave & 3] = s;
                    lnq[row][wave & 3] = q;
                }
            }
        __syncthreads();
#pragma unroll
        for (int i = 0; i < 4; ++i) {
#pragma unroll
            for (int r = 0; r < 4; ++r) {
                int row = wm + i * 16 + quad * 4 + r;
                float s = lns[row][0] + lns[row][1] + lns[row][2] + lns[row][3];
                float q = lnq[row][0] + lnq[row][1] + lnq[row][2] + lnq[row][3];
                float mu = s * (1.0f / HID4);
                float var = q * (1.0f / HID4) - mu * mu;
                float rs = rsqrtf(var + LN_EPS);
                int m = m0 + row;
#pragma unroll
                for (int j = 0; j < 4; ++j) {
                    int col = wn + j * 16 + r16;
                    float v = (acc[i][j][r] - mu) * rs * gamma[col] + beta[col];
                    C[(size_t)m * 512 + col] = f2b(fmaxf(v, 0.0f));
                }
            }
        }
    }
}

// ---------------- normalize ----------------

__global__ void normalize_out(const float* __restrict__ ro, float* __restrict__ out) {
    int g = blockIdx.x;
    int d = threadIdx.x;  // 128 threads = 2 waves
    float v = ro[g * OUT_DIM + d];
    float ss = v * v;
#pragma unroll
    for (int m = 1; m < 64; m <<= 1) ss += __shfl_xor(ss, m);
    __shared__ float s2[2];
    if ((d & 63) == 0) s2[d >> 6] = ss;
    __syncthreads();
    float tot = s2[0] + s2[1];
    float norm = fmaxf(sqrtf(tot), 1e-12f);
    out[g * OUT_DIM + d] = v / norm;
}

// ---------------- launch ----------------

extern "C" void kernel_launch(void* const* d_in, const int* in_sizes, int n_in,
                              void* d_out, int out_size, void* d_ws, size_t ws_size,
                              hipStream_t stream) {
    const float* x    = (const float*)d_in[0];
    const float* w    = (const float*)d_in[1];
    const float* W1   = (const float*)d_in[2];
    const float* fc1W = (const float*)d_in[3];
    const float* gam  = (const float*)d_in[4];
    const float* bet  = (const float*)d_in[5];
    const float* W2   = (const float*)d_in[6];
    const float* W3   = (const float*)d_in[7];
    const int* src = (const int*)d_in[8];
    const int* dst = (const int*)d_in[9];
    const int* gid = (const int*)d_in[10];
    float* out = (float*)d_out;

    float* ws = (float*)d_ws;
    float* out_inv = ws + 0;                                 // 40000
    float* in_inv  = ws + 40000;                             // 40000
    int*   cnt_out = (int*)(ws + 400000);                    // 40000 (memset group start)
    int*   cnt_in  = (int*)(ws + 440000);                    // 40000 (memset group)
    float* ro      = ws + 480000;                            // 8192 (memset group end)
    unsigned short* W1t  = (unsigned short*)(ws + 488192);   // [256][128]
    unsigned short* fc1t = (unsigned short*)(ws + 504576);   // [256][128]
    unsigned short* W2t  = (unsigned short*)(ws + 520960);   // [256][512]
    unsigned short* W3t  = (unsigned short*)(ws + 586496);   // [128][256]
    int*   off     = (int*)(ws + 602920);                    // 40001
    int2*  es1     = (int2*)(ws + 642922);                   // 320000 int2
    int2*  es23    = (int2*)(ws + 1282922);                  // 320000 int2
    unsigned short* xb    = (unsigned short*)(ws + 1923000); // [M_PAD][128] ; later Q3b
    unsigned short* Q3b   = xb;
    unsigned short* agg1b = (unsigned short*)(ws + 4487100); // [M_PAD][128..256] ; later x2b
    unsigned short* x2b   = agg1b;
    unsigned short* x1f1  = (unsigned short*)(ws + 9615300); // [M_PAD][512] interleaved x1|f1
    unsigned short* P2b   = (unsigned short*)(ws + 19871700);// [M_PAD][256]

    // one memset covers cnt_out | cnt_in | ro (contiguous)
    hipMemsetAsync(cnt_out, 0, (2 * 40000 + N_GRAPHS * OUT_DIM) * sizeof(float), stream);

    // fused conversions + degree histograms
    prep_all<<<(PREP_TOT + 255) / 256, 256, 0, stream>>>(x, W1, fc1W, W2, W3, src, dst,
                                                         xb, W1t, fc1t, W2t, W3t,
                                                         cnt_out, cnt_in);
    scan_final<<<40, 1024, 0, stream>>>(cnt_in, cnt_out, off, out_inv, in_inv);
    csr_fill<<<(N_EDGES + 255) / 256, 256, 0, stream>>>(src, dst, w, out_inv, off, cnt_in,
                                                        es1, es23);

    // conv1 gather, then fused conv1+fc1(+LN) GEMM into interleaved x1f1
    gather_nodes<IN_DIM, 0, 4><<<N_NODES / 4, IN_DIM / 2, 0, stream>>>(xb, off, es1, in_inv, agg1b);
    {
        dim3 grid(M_PAD / 128, 1, 2);
        gemm_dual<<<grid, 512, 0, stream>>>(agg1b, W1t, xb, fc1t, x1f1, gam, bet);
    }

    // conv2: single contiguous K=512 A-stream
    {
        dim3 grid(M_PAD / 128, HID4 / 128);
        gemm_mfma<0, 1><<<grid, 256, 0, stream>>>(x1f1, W2t, P2b, out_inv, 512, HID4);
    }
    gather_nodes<HID4, 1, 2><<<N_NODES / 2, HID4 / 2, 0, stream>>>(P2b, off, es23, in_inv, x2b);

    // conv3
    {
        dim3 grid(M_PAD / 128, OUT_DIM / 128);
        gemm_mfma<0, 1><<<grid, 256, 0, stream>>>(x2b, W3t, Q3b, out_inv, HID4, OUT_DIM);
    }
    // conv3 gather fused with readout (x3 never materialized)
    gather3_ro<<<(N_NODES + G3_NPB - 1) / G3_NPB, 64, 0, stream>>>(Q3b, off, es23, in_inv,
                                                                   gid, ro);
    normalize_out<<<N_GRAPHS, 128, 0, stream>>>(ro, out);
}